// Round 6
// baseline (27.358 us; speedup 1.0000x reference)
//
#include <hip/hip_runtime.h>

// BilateralFilter fp32, 8 images 512x512, 3x3, sigma=0.8.
// v6 = v5 (2x4 thread tile, pair-weight symmetry, no shfl, no spill) +
//  (1) XCD-bijective block swizzle: XCD x owns image x -> row-overlap
//      re-reads dedupe in that XCD's private L2.
//  (2) load-early schedule: side-row loads issued before the long pair
//      compute; centers read from intact A/B windows (no center copies).

constexpr int HH = 512;
constexpr int WW = 512;
constexpr int HW = HH * WW;

#define KEXP (-1.1271055f)            // -(1/(2*0.8^2)) * log2(e)
#define E2(x) __builtin_amdgcn_exp2f(x)
#define WS0f 0.2724967f               // normalized spatial gaussian, d2=0
#define WS1f 0.1247577f               // d2=1
#define WS2f 0.0571180f               // d2=2

__global__ __launch_bounds__(256) void bilateral_v6(
    const float* __restrict__ depth,   // [N,1,H,W]
    const float* __restrict__ color,   // [N,3,H,W]
    const float* __restrict__ mask,    // [N,1,H,W]
    float* __restrict__ out)           // [N,3,H,W]
{
    const int lane = threadIdx.x & 63;
    const int b    = blockIdx.x;
    // Bijective XCD swizzle (1024 blocks, 8 XCDs): XCD x gets logical
    // blocks [x*128, (x+1)*128) == image x entirely -> L2 row reuse.
    const int logical = (b & 7) * 128 + (b >> 3);
    const int wg   = logical * 4 + (int)(threadIdx.x >> 6);
    const int n    = wg >> 9;               // image 0..7
    const int rem  = wg & 511;
    const int hp   = rem >> 1;              // row-pair 0..255
    const int half = rem & 1;               // column half
    const int rA   = hp * 2;
    const int c0   = half * 256 + lane * 4;

    const float* dptr = depth + (size_t)n * HW;
    const float* mptr = mask  + (size_t)n * HW;
    const float* xptr = color + (size_t)n * 3 * HW;
    const float* yptr = xptr + HW;
    const float* zptr = xptr + 2 * HW;

    const bool hasL = (c0 > 0);
    const bool hasR = (c0 < WW - 4);

    // Window rows: cols 0..5 = w-1..w+4. D depth, M mask, X/Y/Z color.
    float AD[6], AM[6], AX[6], AY[6], AZ[6];   // row rA
    float BD[6], BM[6], BX[6], BY[6], BZ[6];   // row rA+1
    float PD[6], PM[6], PX[6], PY[6], PZ[6];   // side row (rA-1, then rA+2)

#define LOADP(W, base, ro) do {                                              \
    const float4 _q = *reinterpret_cast<const float4*>((base) + (ro));       \
    W[1] = _q.x; W[2] = _q.y; W[3] = _q.z; W[4] = _q.w;                      \
    W[0] = hasL ? (base)[(ro) - 1] : 0.0f;                                   \
    W[5] = hasR ? (base)[(ro) + 4] : 0.0f;                                   \
} while (0)

#define LOADW(D_, M_, X_, Y_, Z_, r) do {                                    \
    const int _ro = (r) * WW + c0;                                           \
    LOADP(D_, dptr, _ro); LOADP(M_, mptr, _ro);                              \
    LOADP(X_, xptr, _ro); LOADP(Y_, yptr, _ro); LOADP(Z_, zptr, _ro);        \
} while (0)

    // Accumulators (a = row rA, b = row rA+1)
    float aSwd[4], aSwc[4], aSt[4], aS0[4], aS1[4], aS2[4];
    float bSwd[4], bSwc[4], bSt[4], bS0[4], bS1[4], bS2[4];
    #pragma unroll
    for (int i = 0; i < 4; ++i) {
        aSwd[i]=0.f; aSwc[i]=0.f; aSt[i]=0.f; aS0[i]=0.f; aS1[i]=0.f; aS2[i]=0.f;
        bSwd[i]=0.f; bSwc[i]=0.f; bSt[i]=0.f; bS0[i]=0.f; bS1[i]=0.f; bS2[i]=0.f;
    }

// Horizontal pass within one row: center tap + shared E/W pair weights.
#define HPASS(D_, M_, X_, Y_, Z_, Swd, Swc, St, S0, S1, S2) do {             \
    float hwd[5], hwc[5];                                                    \
    _Pragma("unroll") for (int j = 0; j < 5; ++j) {                          \
        const float dd = D_[j] - D_[j + 1];                                  \
        hwd[j] = E2(KEXP * dd * dd);                                         \
        const float f0 = X_[j] - X_[j + 1];                                  \
        const float f1 = Y_[j] - Y_[j + 1];                                  \
        const float f2 = Z_[j] - Z_[j + 1];                                  \
        hwc[j] = E2(KEXP * f0 * f0) + E2(KEXP * f1 * f1)                     \
               + E2(KEXP * f2 * f2);                                         \
    }                                                                        \
    _Pragma("unroll") for (int i = 0; i < 4; ++i) {                          \
        const int ci = i + 1;                                                \
        { const float t = (3.0f * WS0f) * M_[ci];     /* center wd=1 wc=3 */ \
          Swd[i] += 1.0f; Swc[i] += 3.0f; St[i] += t;                        \
          S0[i] += t * X_[ci]; S1[i] += t * Y_[ci]; S2[i] += t * Z_[ci]; }   \
        { const float t = hwd[i] * hwc[i] * WS1f * M_[i];        /* west */  \
          Swd[i] += hwd[i]; Swc[i] += hwc[i]; St[i] += t;                    \
          S0[i] += t * X_[i]; S1[i] += t * Y_[i]; S2[i] += t * Z_[i]; }      \
        { const float t = hwd[i+1] * hwc[i+1] * WS1f * M_[i+2];  /* east */  \
          Swd[i] += hwd[i+1]; Swc[i] += hwc[i+1]; St[i] += t;                \
          S0[i] += t * X_[i+2]; S1[i] += t * Y_[i+2]; S2[i] += t * Z_[i+2];} \
    }                                                                        \
} while (0)

// One-sided pass: side-row window T vs centers taken from intact row window R.
#define SIDE(TD, TM, TX, TY, TZ, RD, RX, RY, RZ, Swd, Swc, St, S0, S1, S2) do { \
    _Pragma("unroll") for (int i = 0; i < 4; ++i) {                          \
        const float cd = RD[i + 1];                                          \
        const float cx = RX[i + 1];                                          \
        const float cy = RY[i + 1];                                          \
        const float cz = RZ[i + 1];                                          \
        _Pragma("unroll") for (int dj = 0; dj < 3; ++dj) {                   \
            const int c = i + dj;                                            \
            const float dd = TD[c] - cd;                                     \
            const float wd = E2(KEXP * dd * dd);                             \
            const float f0 = TX[c] - cx;                                     \
            const float f1 = TY[c] - cy;                                     \
            const float f2 = TZ[c] - cz;                                     \
            const float wc = E2(KEXP * f0 * f0) + E2(KEXP * f1 * f1)         \
                           + E2(KEXP * f2 * f2);                             \
            const float ws = (dj == 1) ? WS1f : WS2f;                        \
            const float t = wd * wc * ws * TM[c];                            \
            Swd[i] += wd; Swc[i] += wc; St[i] += t;                          \
            S0[i] += t * TX[c]; S1[i] += t * TY[c]; S2[i] += t * TZ[c];      \
        }                                                                    \
    }                                                                        \
} while (0)

    const bool hasUp = (hp > 0);      // wave-uniform
    const bool hasDn = (hp < 255);    // wave-uniform

    // Issue all of rows A, B and side row rA-1 up-front.
    LOADW(AD, AM, AX, AY, AZ, rA);
    LOADW(BD, BM, BX, BY, BZ, rA + 1);
    if (hasUp) LOADW(PD, PM, PX, PY, PZ, rA - 1);

    // Compute on A/B while P flies.
    HPASS(AD, AM, AX, AY, AZ, aSwd, aSwc, aSt, aS0, aS1, aS2);
    HPASS(BD, BM, BX, BY, BZ, bSwd, bSwc, bSt, bS0, bS1, bS2);

    if (hasUp) {
        SIDE(PD, PM, PX, PY, PZ, AD, AX, AY, AZ,
             aSwd, aSwc, aSt, aS0, aS1, aS2);
    }

    // Issue row rA+2 into P's registers; the 16-pair GAP below hides it.
    if (hasDn) LOADW(PD, PM, PX, PY, PZ, rA + 2);

    // Vertical + diagonal pairs between rows A and B: computed once,
    // accumulated into both interior endpoints.
    #pragma unroll
    for (int a = 0; a < 6; ++a) {
        #pragma unroll
        for (int db = -1; db <= 1; ++db) {
            const int bb = a + db;
            if (bb < 0 || bb > 5) continue;
            const bool useA = (a >= 1 && a <= 4);
            const bool useB = (bb >= 1 && bb <= 4);
            if (!useA && !useB) continue;
            const float dd = AD[a] - BD[bb];
            const float pwd = E2(KEXP * dd * dd);
            const float f0 = AX[a] - BX[bb];
            const float f1 = AY[a] - BY[bb];
            const float f2 = AZ[a] - BZ[bb];
            const float pwc = E2(KEXP * f0 * f0) + E2(KEXP * f1 * f1)
                            + E2(KEXP * f2 * f2);
            const float g = pwd * pwc;
            const float ws = (db == 0) ? WS1f : WS2f;
            if (useA) {
                const int i = a - 1;
                const float t = g * ws * BM[bb];
                aSwd[i] += pwd; aSwc[i] += pwc; aSt[i] += t;
                aS0[i] += t * BX[bb]; aS1[i] += t * BY[bb]; aS2[i] += t * BZ[bb];
            }
            if (useB) {
                const int i = bb - 1;
                const float t = g * ws * AM[a];
                bSwd[i] += pwd; bSwc[i] += pwc; bSt[i] += t;
                bS0[i] += t * AX[a]; bS1[i] += t * AY[a]; bS2[i] += t * AZ[a];
            }
        }
    }

    if (hasDn) {
        SIDE(PD, PM, PX, PY, PZ, BD, BX, BY, BZ,
             bSwd, bSwc, bSt, bS0, bS1, bS2);
    }
    // (skipped side passes at image top/bottom only omit the zero-pad rows'
    //  contribution to the 9e-7 guard term -> error << 1e-3)

    // out = Stc / (St + 9e-7 * Swd * Swc)
    float oa0[4], oa1[4], oa2[4], ob0[4], ob1[4], ob2[4];
    #pragma unroll
    for (int i = 0; i < 4; ++i) {
        const float invA = __builtin_amdgcn_rcpf(aSt[i] + 9e-7f * aSwd[i] * aSwc[i]);
        oa0[i] = aS0[i] * invA; oa1[i] = aS1[i] * invA; oa2[i] = aS2[i] * invA;
        const float invB = __builtin_amdgcn_rcpf(bSt[i] + 9e-7f * bSwd[i] * bSwc[i]);
        ob0[i] = bS0[i] * invB; ob1[i] = bS1[i] * invB; ob2[i] = bS2[i] * invB;
    }

    float* po = out + (size_t)n * 3 * HW + rA * WW + c0;
    *reinterpret_cast<float4*>(po)               = make_float4(oa0[0], oa0[1], oa0[2], oa0[3]);
    *reinterpret_cast<float4*>(po + HW)          = make_float4(oa1[0], oa1[1], oa1[2], oa1[3]);
    *reinterpret_cast<float4*>(po + 2 * HW)      = make_float4(oa2[0], oa2[1], oa2[2], oa2[3]);
    *reinterpret_cast<float4*>(po + WW)          = make_float4(ob0[0], ob0[1], ob0[2], ob0[3]);
    *reinterpret_cast<float4*>(po + WW + HW)     = make_float4(ob1[0], ob1[1], ob1[2], ob1[3]);
    *reinterpret_cast<float4*>(po + WW + 2 * HW) = make_float4(ob2[0], ob2[1], ob2[2], ob2[3]);
}

extern "C" void kernel_launch(void* const* d_in, const int* in_sizes, int n_in,
                              void* d_out, int out_size, void* d_ws, size_t ws_size,
                              hipStream_t stream) {
    const float* depth = (const float*)d_in[0];
    const float* color = (const float*)d_in[1];
    const float* mask  = (const float*)d_in[2];
    float* out = (float*)d_out;

    // 8 images * 256 row-pairs * 2 halves = 4096 waves; 4 waves/block
    bilateral_v6<<<1024, 256, 0, stream>>>(depth, color, mask, out);
}